// Round 19
// baseline (57.960 us; speedup 1.0000x reference)
//
#include <hip/hip_runtime.h>
#include <hip/hip_bf16.h>

#define B_ 8
#define C_ 256
#define L_ 1024
#define NH_ 8
#define EPS_ 1e-5f

typedef __attribute__((ext_vector_type(8))) _Float16 half8;
typedef __attribute__((ext_vector_type(2))) __fp16 fp16x2;
typedef __attribute__((ext_vector_type(4))) float f32x4;

static __device__ inline ushort f2h(float f) {
  union { _Float16 h; ushort u; } c;
  c.h = (_Float16)f;
  return c.u;
}

// pack two fp32 -> fp16 pair via v_cvt_pkrtz_f16_f32 (compiler builtin --
// safe on TRANS-result inputs, unlike inline asm; rounds 9-11 lesson)
static __device__ inline uint pkh(float a, float b) {
  union { fp16x2 v; uint u; } c;
  c.v = __builtin_amdgcn_cvt_pkrtz(a, b);
  return c.u;
}

// ---------------------------------------------------------------------------
// Kernel A1 (512 thr, grid 640): blocks 0-127: weight fp32->fp16 convert;
// blocks 128-639: GN stats partials -- each block reduces HALF a group
// (4 channels x 1024) and writes (s, ss) to part[sid]. Deterministic.
// ---------------------------------------------------------------------------
__global__ __launch_bounds__(512) void gnstats_kernel(
    const float* __restrict__ x,
    const float4* __restrict__ qw, const float4* __restrict__ ow,
    uint2* __restrict__ wq, uint2* __restrict__ wo_,
    float2* __restrict__ part) {
  int t = threadIdx.x;
  if (blockIdx.x < 128) {
    int id = blockIdx.x * 512 + t;
    float4 v;
    uint2* dst;
    if (id < 49152) { v = qw[id]; dst = wq + id; }
    else { v = ow[id - 49152]; dst = wo_ + (id - 49152); }
    *dst = make_uint2(pkh(v.x, v.y), pkh(v.z, v.w));
    return;
  }
  int sid = blockIdx.x - 128;       // 0..511: G = sid>>1, half = sid&1
  int G = sid >> 1, h = sid & 1;
  int b = G >> 5, gg = G & 31;
  const float4* xb = (const float4*)(x + ((size_t)(b * 256 + gg * 8 + h * 4)) * L_);

  float s = 0.f, ss = 0.f;
#pragma unroll
  for (int i = 0; i < 2; ++i) {
    float4 v = xb[t + 512 * i];
    s += v.x + v.y + v.z + v.w;
    ss += v.x * v.x + v.y * v.y + v.z * v.z + v.w * v.w;
  }
#pragma unroll
  for (int off = 32; off >= 1; off >>= 1) {
    s  += __shfl_xor(s, off);
    ss += __shfl_xor(ss, off);
  }
  __shared__ float ws0[8], ws1[8];
  int wave = t >> 6;
  if ((t & 63) == 0) { ws0[wave] = s; ws1[wave] = ss; }
  __syncthreads();
  if (t == 0) {
    float as = 0.f, ass = 0.f;
#pragma unroll
    for (int i = 0; i < 8; ++i) { as += ws0[i]; ass += ws1[i]; }
    part[sid] = make_float2(as, ass);
  }
}

// ---------------------------------------------------------------------------
// Kernel A2 (256 thr, grid 1024): block = (group G, l-quarter). Combines the
// two stat partials, normalizes the 8x258 halo tile into LDS, does the k=3
// depthwise conv, packs fp16, writes ht [B][32 cg][1024 l][8 c] contiguously.
// ---------------------------------------------------------------------------
__global__ __launch_bounds__(256) void gnapply_kernel(
    const float* __restrict__ x, const float* __restrict__ gamma,
    const float* __restrict__ beta, const float* __restrict__ dw,
    const float2* __restrict__ part, ushort* __restrict__ ht) {
  int j = blockIdx.x;
  int G = j >> 2, ql = j & 3;
  int b = G >> 5, gg = G & 31;
  int l0 = ql * 256;
  int t = threadIdx.x;

  float2 p0 = part[2 * G], p1 = part[2 * G + 1];
  float s = p0.x + p1.x, ss = p0.y + p1.y;
  float mean = s * (1.f / 8192.f);
  float var = ss * (1.f / 8192.f) - mean * mean;
  float rstd = rsqrtf(var + EPS_);

  __shared__ float hn[8][264];    // normalized, halo: lofs = l - (l0-1), 0..257
  const float* xg = x + ((size_t)(b * 256 + gg * 8)) * L_;
#pragma unroll
  for (int c = 0; c < 8; ++c) {
    float sc = gamma[gg * 8 + c] * rstd;
    float bt = beta[gg * 8 + c];
    {
      int l = l0 - 1 + t;
      float v = (l >= 0 && l < L_) ? xg[(size_t)c * L_ + l] : 0.f;
      hn[c][t] = (l >= 0 && l < L_) ? ((v - mean) * sc + bt) : 0.f;
    }
    if (t < 2) {
      int l = l0 + 255 + t;
      float v = (l < L_) ? xg[(size_t)c * L_ + l] : 0.f;
      hn[c][256 + t] = (l < L_) ? ((v - mean) * sc + bt) : 0.f;
    }
  }
  __syncthreads();

  // thread t owns l = l0 + t; conv across l for all 8 channels
  float r[8];
#pragma unroll
  for (int c = 0; c < 8; ++c) {
    int cc = gg * 8 + c;
    float w0 = dw[cc * 3 + 0], w1 = dw[cc * 3 + 1], w2 = dw[cc * 3 + 2];
    r[c] = w0 * hn[c][t] + w1 * hn[c][t + 1] + w2 * hn[c][t + 2];
  }
  uint4 pk;
  pk.x = pkh(r[0], r[1]);
  pk.y = pkh(r[2], r[3]);
  pk.z = pkh(r[4], r[5]);
  pk.w = pkh(r[6], r[7]);
  *(uint4*)(ht + (((size_t)(b * 32 + gg)) * L_ + l0 + t) * 8) = pk;
}

// ---------------------------------------------------------------------------
// Kernel B: qkv pointwise conv via MFMA (fp16), fused repack epilogue.
// Input ht [B][32][1024][8]. Q PRE-SCALED by 1/sqrt(C)*log2(e).
// ---------------------------------------------------------------------------
__global__ __launch_bounds__(256) void qkv_fused_kernel(
    const ushort* __restrict__ Xt, const ushort* __restrict__ Wb,
    const float* __restrict__ bias, ushort* __restrict__ qt,
    ushort* __restrict__ kt, ushort* __restrict__ vb) {
  int bx = blockIdx.x, head = blockIdx.y, b = blockIdx.z;
  int bh = b * 8 + head;
  int t = threadIdx.x;
  int w = t >> 6, l = t & 63;
  int g = l >> 4, ln = l & 15;
  int wl = w >> 1, wo = w & 1;
  int lbase = bx * 128 + wl * 64;

  const ushort* xb = Xt + (size_t)b * (32 * L_ * 8);
  const ushort* wp = Wb + (size_t)(head * 96 + wo * 48) * 256;

  f32x4 acc[4][3];
#pragma unroll
  for (int ml = 0; ml < 4; ++ml)
#pragma unroll
    for (int nn = 0; nn < 3; ++nn) acc[ml][nn] = (f32x4){0.f, 0.f, 0.f, 0.f};

  for (int c0 = 0; c0 < 256; c0 += 32) {
    half8 af[4], bf[3];
#pragma unroll
    for (int ml = 0; ml < 4; ++ml)
      af[ml] = *(const half8*)(xb +
          (((size_t)((c0 >> 3) + g)) * L_ + lbase + 16 * ml + ln) * 8);
#pragma unroll
    for (int nn = 0; nn < 3; ++nn)
      bf[nn] = *(const half8*)(wp + (size_t)(16 * nn + ln) * 256 + c0 + 8 * g);
#pragma unroll
    for (int ml = 0; ml < 4; ++ml)
#pragma unroll
      for (int nn = 0; nn < 3; ++nn)
        acc[ml][nn] = __builtin_amdgcn_mfma_f32_16x16x32_f16(af[ml], bf[nn], acc[ml][nn], 0, 0, 0);
  }

  // bias
#pragma unroll
  for (int nn = 0; nn < 3; ++nn) {
    float bs = bias[head * 96 + wo * 48 + 16 * nn + ln];
#pragma unroll
    for (int ml = 0; ml < 4; ++ml)
#pragma unroll
      for (int r = 0; r < 4; ++r) acc[ml][nn][r] += bs;
  }

  __shared__ ushort tr[5120];
  const float QSC = 0.0625f * 1.44269504f;   // 1/sqrt(256) * log2(e)

  // rounds 0 (q, scaled), 1 (k): transpose to [l][d] (pad 40), write [bh][l][32]
  for (int rk = 0; rk < 2; ++rk) {
    float sc = rk ? 1.f : QSC;
    __syncthreads();
#pragma unroll
    for (int nn = 0; nn < 3; ++nn) {
      int ocl0 = wo * 48 + 16 * nn;
      if (ocl0 >= rk * 32 && ocl0 < rk * 32 + 32) {
        int d = ocl0 - rk * 32 + ln;
#pragma unroll
        for (int ml = 0; ml < 4; ++ml) {
          int lrow = wl * 64 + 16 * ml + 4 * g;
#pragma unroll
          for (int r = 0; r < 4; ++r)
            tr[(lrow + r) * 40 + d] = f2h(acc[ml][nn][r] * sc);
        }
      }
    }
    __syncthreads();
    {
      int row = t >> 1, half = t & 1;
      uint4 v0 = *(const uint4*)&tr[row * 40 + half * 16];
      uint4 v1 = *(const uint4*)&tr[row * 40 + half * 16 + 8];
      ushort* dst = (rk ? kt : qt) +
                    ((size_t)bh * L_ + bx * 128 + row) * 32 + half * 16;
      *(uint4*)dst = v0;
      *(uint4*)(dst + 8) = v1;
    }
  }

  // round 2 (v): [d][l] (pad 136), PI-permute on global write
  __syncthreads();
  if (wo == 1) {
#pragma unroll
    for (int nn = 1; nn < 3; ++nn) {
      int d = 16 * (nn - 1) + ln;
#pragma unroll
      for (int ml = 0; ml < 4; ++ml) {
        int lc = wl * 64 + 16 * ml + 4 * g;
        *(uint2*)&tr[d * 136 + lc] =
            make_uint2(pkh(acc[ml][nn][0], acc[ml][nn][1]),
                       pkh(acc[ml][nn][2], acc[ml][nn][3]));
      }
    }
  }
  __syncthreads();
  {
    int d = t >> 3, s0 = t & 7;
    ushort* vdst = vb + ((size_t)bh * 32 + d) * L_ + bx * 128;
#pragma unroll
    for (int c = 0; c < 2; ++c) {
      int ch = s0 + 8 * c;
      int jj = ch >> 2, gg = ch & 3;
      uint2 lo = *(const uint2*)&tr[d * 136 + 32 * jj + 4 * gg];
      uint2 hi = *(const uint2*)&tr[d * 136 + 32 * jj + 16 + 4 * gg];
      *(uint4*)(vdst + 32 * jj + 8 * gg) = make_uint4(lo.x, lo.y, hi.x, hi.y);
    }
  }
}

// ---------------------------------------------------------------------------
// Kernel D: out pointwise conv via MFMA (fp16) + residual. Input ot
// [bh][1024][32]. Block = 128 l x 64 oc. grid (8, 4, B) = 256.
// ---------------------------------------------------------------------------
__global__ __launch_bounds__(256) void outconv_kernel(
    const ushort* __restrict__ Xt, const ushort* __restrict__ Wb,
    const float* __restrict__ bias, const float* __restrict__ resid,
    float* __restrict__ out) {
  int b = blockIdx.z;
  int t = threadIdx.x;
  int w = t >> 6, l = t & 63;
  int g = l >> 4, ln = l & 15;
  int lbase = blockIdx.x * 128;
  int ocblk = blockIdx.y * 64;
  int ocbase = ocblk + w * 16;

  const ushort* xb = Xt + (size_t)b * (8 * L_ * 32);
  const ushort* wp = Wb + (size_t)ocbase * 256;

  f32x4 acc[8];
#pragma unroll
  for (int ml = 0; ml < 8; ++ml) acc[ml] = (f32x4){0.f, 0.f, 0.f, 0.f};

  for (int c0 = 0; c0 < 256; c0 += 32) {
    half8 af[8];
#pragma unroll
    for (int ml = 0; ml < 8; ++ml)
      af[ml] = *(const half8*)(xb +
          ((size_t)(c0 >> 5) * L_ + lbase + 16 * ml + ln) * 32 + 8 * g);
    half8 bf = *(const half8*)(wp + (size_t)ln * 256 + c0 + 8 * g);
#pragma unroll
    for (int ml = 0; ml < 8; ++ml)
      acc[ml] = __builtin_amdgcn_mfma_f32_16x16x32_f16(af[ml], bf, acc[ml], 0, 0, 0);
  }

  __shared__ float tile[64][132];   // 33 KB
  float bs = bias[ocbase + ln];
#pragma unroll
  for (int ml = 0; ml < 8; ++ml) {
    int ll = 16 * ml + 4 * g;
    float4 v = make_float4(acc[ml][0] + bs, acc[ml][1] + bs,
                           acc[ml][2] + bs, acc[ml][3] + bs);
    *(float4*)&tile[w * 16 + ln][ll] = v;
  }
  __syncthreads();
  {
    int ocl = t >> 2, lq = t & 3;           // 64 oc x 4 l-chunks of 32
    const float* src = &tile[ocl][lq * 32];
    size_t ob = ((size_t)b * 256 + ocblk + ocl) * L_ + lbase + lq * 32;
#pragma unroll
    for (int i = 0; i < 8; ++i) {
      float4 v = *(const float4*)(src + 4 * i);
      float4 rd = *(const float4*)(resid + ob + 4 * i);
      v.x += rd.x; v.y += rd.y; v.z += rd.z; v.w += rd.w;
      *(float4*)(out + ob + 4 * i) = v;
    }
  }
}

// ---------------------------------------------------------------------------
// Kernel C: MFMA flash attention, 8 waves x 16q = 128q per block (512 thr).
// fp16 pipeline, no max-subtraction, exp via v_exp_f32, pack via cvt_pkrtz.
// dbuf K+V LDS staging, padded layouts, otile overlays K0. grid 512.
// ---------------------------------------------------------------------------
__global__ __launch_bounds__(512) void attn_mfma_kernel(
    const ushort* __restrict__ qt, const ushort* __restrict__ kt,
    const ushort* __restrict__ vb, ushort* __restrict__ ot) {
  const int id = blockIdx.x;
  const int bh = ((id & 7) << 3) | (id >> 6);
  const int qtile = (id >> 3) & 7;
  const int t = threadIdx.x;
  const int w = t >> 6, l = t & 63;
  const int g = l >> 4, ln = l & 15;
  const int q0b = qtile * 128;
  const int q0 = q0b + w * 16;

  // smem (ushorts): K0 @0 (5120), K1 @5120, V0 @10240 (4352), V1 @14592.
  // otile [128][40] = 5120 overlays K0 (dead in tt=7 / epilogue).
  __shared__ __align__(16) ushort smem[18944];   // 37,888 B

  const ushort* qbase = qt + (size_t)bh * (L_ * 32);
  const ushort* kbase = kt + (size_t)bh * (L_ * 32);
  const ushort* vbase = vb + (size_t)bh * (32 * L_);

  // staging geometry (512 threads, 1 x 16B each for K and V per tile)
  const int krow = t >> 2, kchunk = t & 3;           // K: 128 rows x 4 chunks
  const ushort* kg = kbase + krow * 32 + kchunk * 8;
  const int kwo = krow * 40 + kchunk * 8;
  const int vrow = t >> 4, vchunk = t & 15;          // V: 32 rows x 16 chunks
  const ushort* vg = vbase + (size_t)vrow * L_ + vchunk * 8;
  const int vwo = vrow * 136 + vchunk * 8;

  const f32x4 z4 = {0.f, 0.f, 0.f, 0.f};
  const half8 bq = *(const half8*)(qbase + (size_t)(q0 + ln) * 32 + g * 8);

  union { ushort s[8]; half8 v; } onesu;
#pragma unroll
  for (int i = 0; i < 8; ++i) onesu.s[i] = 0x3C00;  // fp16 1.0
  const half8 ones = onesu.v;

  f32x4 oacc[2] = {z4, z4};   // [md]
  f32x4 oaccS = z4;

  // prologue: stage tile 0
  uint4 ka0, va0;
  ka0 = *(const uint4*)kg;
  va0 = *(const uint4*)vg;
  __builtin_amdgcn_sched_barrier(0);
  *(uint4*)&smem[kwo] = ka0;
  *(uint4*)&smem[10240 + vwo] = va0;
  asm volatile("s_waitcnt lgkmcnt(0)" ::: "memory");
  __builtin_amdgcn_s_barrier();
  __builtin_amdgcn_sched_barrier(0);

  for (int tt = 0; tt < 8; ++tt) {
    const int cur = tt & 1;
    if (tt < 7) {
      ka0 = *(const uint4*)(kg + (tt + 1) * 4096);
      va0 = *(const uint4*)(vg + (tt + 1) * 128);
    }
    __builtin_amdgcn_sched_barrier(0);

    const ushort* Kc = &smem[cur * 5120];
    const ushort* Vc = &smem[10240 + cur * 4352];

    // QK^T  (S already in log2-units thanks to Q pre-scale)
    f32x4 sacc[8];
#pragma unroll
    for (int mk = 0; mk < 8; ++mk) {
      half8 ak = *(const half8*)(Kc + (16 * mk + ln) * 40 + g * 8);
      sacc[mk] = __builtin_amdgcn_mfma_f32_16x16x32_f16(ak, bq, z4, 0, 0, 0);
    }

    // exp via v_exp_f32; pack pairs via cvt_pkrtz (compiler builtin -- safe
    // TRANS consumer)
    uint upk[8][2];
#pragma unroll
    for (int mk = 0; mk < 8; ++mk) {
      float e0 = __builtin_amdgcn_exp2f(sacc[mk][0]);
      float e1 = __builtin_amdgcn_exp2f(sacc[mk][1]);
      float e2 = __builtin_amdgcn_exp2f(sacc[mk][2]);
      float e3 = __builtin_amdgcn_exp2f(sacc[mk][3]);
      upk[mk][0] = pkh(e0, e1);
      upk[mk][1] = pkh(e2, e3);
    }

    // PV + denominator
#pragma unroll
    for (int ks = 0; ks < 4; ++ks) {
      union { uint u[4]; half8 v; } pb;
      pb.u[0] = upk[2 * ks][0];     pb.u[1] = upk[2 * ks][1];
      pb.u[2] = upk[2 * ks + 1][0]; pb.u[3] = upk[2 * ks + 1][1];
      oaccS = __builtin_amdgcn_mfma_f32_16x16x32_f16(ones, pb.v, oaccS, 0, 0, 0);
#pragma unroll
      for (int md = 0; md < 2; ++md) {
        half8 av = *(const half8*)(Vc + (16 * md + ln) * 136 + 32 * ks + 8 * g);
        oacc[md] = __builtin_amdgcn_mfma_f32_16x16x32_f16(av, pb.v, oacc[md], 0, 0, 0);
      }
    }

    __builtin_amdgcn_sched_barrier(0);
    if (tt < 7) {
      const int nxt = cur ^ 1;
      *(uint4*)&smem[nxt * 5120 + kwo] = ka0;
      *(uint4*)&smem[10240 + nxt * 4352 + vwo] = va0;
      asm volatile("s_waitcnt lgkmcnt(0)" ::: "memory");
      __builtin_amdgcn_s_barrier();
      __builtin_amdgcn_sched_barrier(0);
    }
  }

  // epilogue: normalize, LDS transpose (otile overlays K0), write ot[bh][l][32]
  ushort* otile = &smem[0];   // [128][40]
  float rl = 1.f / oaccS[0];
  int q_loc = w * 16 + ln;
#pragma unroll
  for (int md = 0; md < 2; ++md) {
    uint2 pk = make_uint2(pkh(oacc[md][0] * rl, oacc[md][1] * rl),
                          pkh(oacc[md][2] * rl, oacc[md][3] * rl));
    *(uint2*)&otile[q_loc * 40 + 16 * md + 4 * g] = pk;
  }
  __syncthreads();
  {
    int row = t >> 2, qu = t & 3;
    uint4 v = *(const uint4*)&otile[row * 40 + qu * 8];
    *(uint4*)(ot + ((size_t)bh * L_ + q0b + row) * 32 + qu * 8) = v;
  }
}

// ---------------------------------------------------------------------------
extern "C" void kernel_launch(void* const* d_in, const int* in_sizes, int n_in,
                              void* d_out, int out_size, void* d_ws, size_t ws_size,
                              hipStream_t stream) {
  const float* x      = (const float*)d_in[0];
  const float* gamma  = (const float*)d_in[1];
  const float* beta   = (const float*)d_in[2];
  const float* dw     = (const float*)d_in[3];
  const float* qkv_w  = (const float*)d_in[4];
  const float* qkv_b  = (const float*)d_in[5];
  const float* out_w  = (const float*)d_in[6];
  const float* out_b  = (const float*)d_in[7];
  float* out = (float*)d_out;

  char* ws = (char*)d_ws;
  ushort* ht   = (ushort*)(ws);                   // 4 MiB @0  (dead after qkv)
  ushort* qtb  = (ushort*)(ws + (16u << 20));     // 4 MiB @16
  ushort* ktb  = (ushort*)(ws + (20u << 20));     // 4 MiB @20
  ushort* vbb  = (ushort*)(ws + (24u << 20));     // 4 MiB @24
  ushort* otb  = (ushort*)(ws);                   // 4 MiB @0  (reuse ht)
  ushort* wq   = (ushort*)(ws + (28u << 20));     // 384 KiB @28M
  ushort* wo   = (ushort*)(ws + (28u << 20) + (512u << 10));  // 128 KiB
  float2* part = (float2*)(ws + (31u << 20));     // 4 KiB @31M

  gnstats_kernel<<<640, 512, 0, stream>>>(x, (const float4*)qkv_w,
                                          (const float4*)out_w,
                                          (uint2*)wq, (uint2*)wo, part);
  gnapply_kernel<<<1024, 256, 0, stream>>>(x, gamma, beta, dw, part, ht);
  qkv_fused_kernel<<<dim3(8, 8, B_), 256, 0, stream>>>(ht, wq, qkv_b, qtb, ktb, vbb);
  attn_mfma_kernel<<<512, 512, 0, stream>>>(qtb, ktb, vbb, otb);
  outconv_kernel<<<dim3(8, 4, B_), 256, 0, stream>>>(otb, wo, out_b, x, out);
}

// Round 20
// 56.828 us; speedup vs baseline: 1.0199x; 1.0199x over previous
//
#include <hip/hip_runtime.h>
#include <hip/hip_bf16.h>

#define B_ 8
#define C_ 256
#define L_ 1024
#define NH_ 8
#define EPS_ 1e-5f

typedef __attribute__((ext_vector_type(8))) _Float16 half8;
typedef __attribute__((ext_vector_type(2))) __fp16 fp16x2;
typedef __attribute__((ext_vector_type(4))) float f32x4;

static __device__ inline ushort f2h(float f) {
  union { _Float16 h; ushort u; } c;
  c.h = (_Float16)f;
  return c.u;
}

// pack two fp32 -> fp16 pair via v_cvt_pkrtz_f16_f32 (compiler builtin --
// safe on TRANS-result inputs, unlike inline asm; rounds 9-11 lesson)
static __device__ inline uint pkh(float a, float b) {
  union { fp16x2 v; uint u; } c;
  c.v = __builtin_amdgcn_cvt_pkrtz(a, b);
  return c.u;
}

// ---------------------------------------------------------------------------
// Kernel A (512 threads): blocks 0-127: weight fp32->fp16 convert;
// blocks 128-383: GroupNorm + depthwise conv k=3. ht [B][32 cg][1024 l][8 c].
// (round-18 monolithic version -- the round-19 two-kernel split regressed)
// ---------------------------------------------------------------------------
__global__ __launch_bounds__(512) void gnw_kernel(
    const float* __restrict__ x, const float* __restrict__ gamma,
    const float* __restrict__ beta, const float* __restrict__ dw,
    const float4* __restrict__ qw, const float4* __restrict__ ow,
    uint2* __restrict__ wq, uint2* __restrict__ wo_,
    ushort* __restrict__ ht) {
  __shared__ float hn[8 * L_];
  __shared__ float ws0[8], ws1[8];
  int t = threadIdx.x;
  if (blockIdx.x < 128) {
    int id = blockIdx.x * 512 + t;
    float4 v;
    uint2* dst;
    if (id < 49152) { v = qw[id]; dst = wq + id; }
    else { v = ow[id - 49152]; dst = wo_ + (id - 49152); }
    *dst = make_uint2(pkh(v.x, v.y), pkh(v.z, v.w));
    return;
  }
  int blk = blockIdx.x - 128;     // b*32 + g
  int b = blk >> 5, g = blk & 31;
  const size_t base = ((size_t)(b * C_ + g * 8)) * L_;

  float s = 0.f, ss = 0.f;
  float vals[16];
#pragma unroll
  for (int i = 0; i < 16; ++i) {
    int e = t + 512 * i;
    float v = x[base + e];
    vals[i] = v;
    s += v; ss += v * v;
  }
#pragma unroll
  for (int off = 32; off >= 1; off >>= 1) {
    s  += __shfl_xor(s, off);
    ss += __shfl_xor(ss, off);
  }
  int wave = t >> 6;
  if ((t & 63) == 0) { ws0[wave] = s; ws1[wave] = ss; }
  __syncthreads();
  s = 0.f; ss = 0.f;
#pragma unroll
  for (int i = 0; i < 8; ++i) { s += ws0[i]; ss += ws1[i]; }
  float mean = s * (1.f / 8192.f);
  float var = ss * (1.f / 8192.f) - mean * mean;
  float rstd = rsqrtf(var + EPS_);

#pragma unroll
  for (int i = 0; i < 16; ++i) {
    int e = t + 512 * i;
    int c = g * 8 + (i >> 1);
    float sc = gamma[c] * rstd;
    hn[e] = (vals[i] - mean) * sc + beta[c];
  }
  __syncthreads();
  float r[16];
#pragma unroll
  for (int i = 0; i < 16; ++i) {
    int e = t + 512 * i;
    int l = e & 1023;
    int c = g * 8 + (i >> 1);
    float w0 = dw[c * 3 + 0], w1 = dw[c * 3 + 1], w2 = dw[c * 3 + 2];
    float a = (l > 0) ? hn[e - 1] : 0.f;
    float m = hn[e];
    float z = (l < 1023) ? hn[e + 1] : 0.f;
    r[i] = w0 * a + w1 * m + w2 * z;
  }
#pragma unroll
  for (int li = 0; li < 2; ++li) {
    int l = t + 512 * li;
    uint4 pk;
    pk.x = pkh(r[0 + li],  r[2 + li]);
    pk.y = pkh(r[4 + li],  r[6 + li]);
    pk.z = pkh(r[8 + li],  r[10 + li]);
    pk.w = pkh(r[12 + li], r[14 + li]);
    *(uint4*)(ht + (((size_t)(b * 32 + g)) * L_ + l) * 8) = pk;
  }
}

// ---------------------------------------------------------------------------
// Kernel B: qkv pointwise conv via MFMA (fp16), fused repack epilogue.
// RE-TILED for occupancy: block = 64l x 96oc (4 waves of 32l x 48oc),
// grid (16 ltile, 8 head, 8 b) = 1024 blocks -> 4 blocks/CU, 4 waves/SIMD.
// Input ht [B][32][1024][8]. Q PRE-SCALED by 1/sqrt(C)*log2(e).
// ---------------------------------------------------------------------------
__global__ __launch_bounds__(256) void qkv_fused_kernel(
    const ushort* __restrict__ Xt, const ushort* __restrict__ Wb,
    const float* __restrict__ bias, ushort* __restrict__ qt,
    ushort* __restrict__ kt, ushort* __restrict__ vb) {
  int bx = blockIdx.x, head = blockIdx.y, b = blockIdx.z;
  int bh = b * 8 + head;
  int t = threadIdx.x;
  int w = t >> 6, l = t & 63;
  int g = l >> 4, ln = l & 15;
  int wl = w >> 1, wo = w & 1;
  int lbase = bx * 64 + wl * 32;

  const ushort* xb = Xt + (size_t)b * (32 * L_ * 8);
  const ushort* wp = Wb + (size_t)(head * 96 + wo * 48) * 256;

  f32x4 acc[2][3];
#pragma unroll
  for (int ml = 0; ml < 2; ++ml)
#pragma unroll
    for (int nn = 0; nn < 3; ++nn) acc[ml][nn] = (f32x4){0.f, 0.f, 0.f, 0.f};

  for (int c0 = 0; c0 < 256; c0 += 32) {
    half8 af[2], bf[3];
#pragma unroll
    for (int ml = 0; ml < 2; ++ml)
      af[ml] = *(const half8*)(xb +
          (((size_t)((c0 >> 3) + g)) * L_ + lbase + 16 * ml + ln) * 8);
#pragma unroll
    for (int nn = 0; nn < 3; ++nn)
      bf[nn] = *(const half8*)(wp + (size_t)(16 * nn + ln) * 256 + c0 + 8 * g);
#pragma unroll
    for (int ml = 0; ml < 2; ++ml)
#pragma unroll
      for (int nn = 0; nn < 3; ++nn)
        acc[ml][nn] = __builtin_amdgcn_mfma_f32_16x16x32_f16(af[ml], bf[nn], acc[ml][nn], 0, 0, 0);
  }

  // bias
#pragma unroll
  for (int nn = 0; nn < 3; ++nn) {
    float bs = bias[head * 96 + wo * 48 + 16 * nn + ln];
#pragma unroll
    for (int ml = 0; ml < 2; ++ml)
#pragma unroll
      for (int r = 0; r < 4; ++r) acc[ml][nn][r] += bs;
  }

  __shared__ ushort tr[2560];
  const float QSC = 0.0625f * 1.44269504f;   // 1/sqrt(256) * log2(e)

  // rounds 0 (q, scaled), 1 (k): transpose to [l][d] (pad 40), write [bh][l][32]
  for (int rk = 0; rk < 2; ++rk) {
    float sc = rk ? 1.f : QSC;
    __syncthreads();
#pragma unroll
    for (int nn = 0; nn < 3; ++nn) {
      int ocl0 = wo * 48 + 16 * nn;
      if (ocl0 >= rk * 32 && ocl0 < rk * 32 + 32) {
        int d = ocl0 - rk * 32 + ln;
#pragma unroll
        for (int ml = 0; ml < 2; ++ml) {
          int lrow = wl * 32 + 16 * ml + 4 * g;
#pragma unroll
          for (int r = 0; r < 4; ++r)
            tr[(lrow + r) * 40 + d] = f2h(acc[ml][nn][r] * sc);
        }
      }
    }
    __syncthreads();
    {
      int row = t >> 2, qu = t & 3;
      uint4 v = *(const uint4*)&tr[row * 40 + qu * 8];
      *(uint4*)((rk ? kt : qt) +
                ((size_t)bh * L_ + bx * 64 + row) * 32 + qu * 8) = v;
    }
  }

  // round 2 (v): [d][l] (pad 72), PI-permute on global write
  __syncthreads();
  if (wo == 1) {
#pragma unroll
    for (int nn = 1; nn < 3; ++nn) {
      int d = 16 * (nn - 1) + ln;
#pragma unroll
      for (int ml = 0; ml < 2; ++ml) {
        int lc = wl * 32 + 16 * ml + 4 * g;
        *(uint2*)&tr[d * 72 + lc] =
            make_uint2(pkh(acc[ml][nn][0], acc[ml][nn][1]),
                       pkh(acc[ml][nn][2], acc[ml][nn][3]));
      }
    }
  }
  __syncthreads();
  {
    int d = t >> 3, ch = t & 7;
    int jj = ch >> 2, gg = ch & 3;
    uint2 lo = *(const uint2*)&tr[d * 72 + 32 * jj + 4 * gg];
    uint2 hi = *(const uint2*)&tr[d * 72 + 32 * jj + 16 + 4 * gg];
    ushort* vdst = vb + ((size_t)bh * 32 + d) * L_ + bx * 64;
    *(uint4*)(vdst + 32 * jj + 8 * gg) = make_uint4(lo.x, lo.y, hi.x, hi.y);
  }
}

// ---------------------------------------------------------------------------
// Kernel D: out pointwise conv via MFMA (fp16) + residual. Input ot
// [bh][1024][32]. Block = 128 l x 64 oc. grid (8, 4, B) = 256.
// ---------------------------------------------------------------------------
__global__ __launch_bounds__(256) void outconv_kernel(
    const ushort* __restrict__ Xt, const ushort* __restrict__ Wb,
    const float* __restrict__ bias, const float* __restrict__ resid,
    float* __restrict__ out) {
  int b = blockIdx.z;
  int t = threadIdx.x;
  int w = t >> 6, l = t & 63;
  int g = l >> 4, ln = l & 15;
  int lbase = blockIdx.x * 128;
  int ocblk = blockIdx.y * 64;
  int ocbase = ocblk + w * 16;

  const ushort* xb = Xt + (size_t)b * (8 * L_ * 32);
  const ushort* wp = Wb + (size_t)ocbase * 256;

  f32x4 acc[8];
#pragma unroll
  for (int ml = 0; ml < 8; ++ml) acc[ml] = (f32x4){0.f, 0.f, 0.f, 0.f};

  for (int c0 = 0; c0 < 256; c0 += 32) {
    half8 af[8];
#pragma unroll
    for (int ml = 0; ml < 8; ++ml)
      af[ml] = *(const half8*)(xb +
          ((size_t)(c0 >> 5) * L_ + lbase + 16 * ml + ln) * 32 + 8 * g);
    half8 bf = *(const half8*)(wp + (size_t)ln * 256 + c0 + 8 * g);
#pragma unroll
    for (int ml = 0; ml < 8; ++ml)
      acc[ml] = __builtin_amdgcn_mfma_f32_16x16x32_f16(af[ml], bf, acc[ml], 0, 0, 0);
  }

  __shared__ float tile[64][132];   // 33 KB
  float bs = bias[ocbase + ln];
#pragma unroll
  for (int ml = 0; ml < 8; ++ml) {
    int ll = 16 * ml + 4 * g;
    float4 v = make_float4(acc[ml][0] + bs, acc[ml][1] + bs,
                           acc[ml][2] + bs, acc[ml][3] + bs);
    *(float4*)&tile[w * 16 + ln][ll] = v;
  }
  __syncthreads();
  {
    int ocl = t >> 2, lq = t & 3;           // 64 oc x 4 l-chunks of 32
    const float* src = &tile[ocl][lq * 32];
    size_t ob = ((size_t)b * 256 + ocblk + ocl) * L_ + lbase + lq * 32;
#pragma unroll
    for (int i = 0; i < 8; ++i) {
      float4 v = *(const float4*)(src + 4 * i);
      float4 rd = *(const float4*)(resid + ob + 4 * i);
      v.x += rd.x; v.y += rd.y; v.z += rd.z; v.w += rd.w;
      *(float4*)(out + ob + 4 * i) = v;
    }
  }
}

// ---------------------------------------------------------------------------
// Kernel C: MFMA flash attention, 8 waves x 16q = 128q per block (512 thr).
// fp16 pipeline, no max-subtraction, exp via v_exp_f32, pack via cvt_pkrtz.
// dbuf K+V LDS staging, padded layouts, otile overlays K0. grid 512.
// ---------------------------------------------------------------------------
__global__ __launch_bounds__(512) void attn_mfma_kernel(
    const ushort* __restrict__ qt, const ushort* __restrict__ kt,
    const ushort* __restrict__ vb, ushort* __restrict__ ot) {
  const int id = blockIdx.x;
  const int bh = ((id & 7) << 3) | (id >> 6);
  const int qtile = (id >> 3) & 7;
  const int t = threadIdx.x;
  const int w = t >> 6, l = t & 63;
  const int g = l >> 4, ln = l & 15;
  const int q0b = qtile * 128;
  const int q0 = q0b + w * 16;

  // smem (ushorts): K0 @0 (5120), K1 @5120, V0 @10240 (4352), V1 @14592.
  // otile [128][40] = 5120 overlays K0 (dead in tt=7 / epilogue).
  __shared__ __align__(16) ushort smem[18944];   // 37,888 B

  const ushort* qbase = qt + (size_t)bh * (L_ * 32);
  const ushort* kbase = kt + (size_t)bh * (L_ * 32);
  const ushort* vbase = vb + (size_t)bh * (32 * L_);

  // staging geometry (512 threads, 1 x 16B each for K and V per tile)
  const int krow = t >> 2, kchunk = t & 3;           // K: 128 rows x 4 chunks
  const ushort* kg = kbase + krow * 32 + kchunk * 8;
  const int kwo = krow * 40 + kchunk * 8;
  const int vrow = t >> 4, vchunk = t & 15;          // V: 32 rows x 16 chunks
  const ushort* vg = vbase + (size_t)vrow * L_ + vchunk * 8;
  const int vwo = vrow * 136 + vchunk * 8;

  const f32x4 z4 = {0.f, 0.f, 0.f, 0.f};
  const half8 bq = *(const half8*)(qbase + (size_t)(q0 + ln) * 32 + g * 8);

  union { ushort s[8]; half8 v; } onesu;
#pragma unroll
  for (int i = 0; i < 8; ++i) onesu.s[i] = 0x3C00;  // fp16 1.0
  const half8 ones = onesu.v;

  f32x4 oacc[2] = {z4, z4};   // [md]
  f32x4 oaccS = z4;

  // prologue: stage tile 0
  uint4 ka0, va0;
  ka0 = *(const uint4*)kg;
  va0 = *(const uint4*)vg;
  __builtin_amdgcn_sched_barrier(0);
  *(uint4*)&smem[kwo] = ka0;
  *(uint4*)&smem[10240 + vwo] = va0;
  asm volatile("s_waitcnt lgkmcnt(0)" ::: "memory");
  __builtin_amdgcn_s_barrier();
  __builtin_amdgcn_sched_barrier(0);

  for (int tt = 0; tt < 8; ++tt) {
    const int cur = tt & 1;
    if (tt < 7) {
      ka0 = *(const uint4*)(kg + (tt + 1) * 4096);
      va0 = *(const uint4*)(vg + (tt + 1) * 128);
    }
    __builtin_amdgcn_sched_barrier(0);

    const ushort* Kc = &smem[cur * 5120];
    const ushort* Vc = &smem[10240 + cur * 4352];

    // QK^T  (S already in log2-units thanks to Q pre-scale)
    f32x4 sacc[8];
#pragma unroll
    for (int mk = 0; mk < 8; ++mk) {
      half8 ak = *(const half8*)(Kc + (16 * mk + ln) * 40 + g * 8);
      sacc[mk] = __builtin_amdgcn_mfma_f32_16x16x32_f16(ak, bq, z4, 0, 0, 0);
    }

    // exp via v_exp_f32; pack pairs via cvt_pkrtz (compiler builtin -- safe
    // TRANS consumer)
    uint upk[8][2];
#pragma unroll
    for (int mk = 0; mk < 8; ++mk) {
      float e0 = __builtin_amdgcn_exp2f(sacc[mk][0]);
      float e1 = __builtin_amdgcn_exp2f(sacc[mk][1]);
      float e2 = __builtin_amdgcn_exp2f(sacc[mk][2]);
      float e3 = __builtin_amdgcn_exp2f(sacc[mk][3]);
      upk[mk][0] = pkh(e0, e1);
      upk[mk][1] = pkh(e2, e3);
    }

    // PV + denominator
#pragma unroll
    for (int ks = 0; ks < 4; ++ks) {
      union { uint u[4]; half8 v; } pb;
      pb.u[0] = upk[2 * ks][0];     pb.u[1] = upk[2 * ks][1];
      pb.u[2] = upk[2 * ks + 1][0]; pb.u[3] = upk[2 * ks + 1][1];
      oaccS = __builtin_amdgcn_mfma_f32_16x16x32_f16(ones, pb.v, oaccS, 0, 0, 0);
#pragma unroll
      for (int md = 0; md < 2; ++md) {
        half8 av = *(const half8*)(Vc + (16 * md + ln) * 136 + 32 * ks + 8 * g);
        oacc[md] = __builtin_amdgcn_mfma_f32_16x16x32_f16(av, pb.v, oacc[md], 0, 0, 0);
      }
    }

    __builtin_amdgcn_sched_barrier(0);
    if (tt < 7) {
      const int nxt = cur ^ 1;
      *(uint4*)&smem[nxt * 5120 + kwo] = ka0;
      *(uint4*)&smem[10240 + nxt * 4352 + vwo] = va0;
      asm volatile("s_waitcnt lgkmcnt(0)" ::: "memory");
      __builtin_amdgcn_s_barrier();
      __builtin_amdgcn_sched_barrier(0);
    }
  }

  // epilogue: normalize, LDS transpose (otile overlays K0), write ot[bh][l][32]
  ushort* otile = &smem[0];   // [128][40]
  float rl = 1.f / oaccS[0];
  int q_loc = w * 16 + ln;
#pragma unroll
  for (int md = 0; md < 2; ++md) {
    uint2 pk = make_uint2(pkh(oacc[md][0] * rl, oacc[md][1] * rl),
                          pkh(oacc[md][2] * rl, oacc[md][3] * rl));
    *(uint2*)&otile[q_loc * 40 + 16 * md + 4 * g] = pk;
  }
  __syncthreads();
  {
    int row = t >> 2, qu = t & 3;
    uint4 v = *(const uint4*)&otile[row * 40 + qu * 8];
    *(uint4*)(ot + ((size_t)bh * L_ + q0b + row) * 32 + qu * 8) = v;
  }
}

// ---------------------------------------------------------------------------
extern "C" void kernel_launch(void* const* d_in, const int* in_sizes, int n_in,
                              void* d_out, int out_size, void* d_ws, size_t ws_size,
                              hipStream_t stream) {
  const float* x      = (const float*)d_in[0];
  const float* gamma  = (const float*)d_in[1];
  const float* beta   = (const float*)d_in[2];
  const float* dw     = (const float*)d_in[3];
  const float* qkv_w  = (const float*)d_in[4];
  const float* qkv_b  = (const float*)d_in[5];
  const float* out_w  = (const float*)d_in[6];
  const float* out_b  = (const float*)d_in[7];
  float* out = (float*)d_out;

  char* ws = (char*)d_ws;
  ushort* ht   = (ushort*)(ws);                   // 4 MiB @0  (dead after qkv)
  ushort* qtb  = (ushort*)(ws + (16u << 20));     // 4 MiB @16
  ushort* ktb  = (ushort*)(ws + (20u << 20));     // 4 MiB @20
  ushort* vbb  = (ushort*)(ws + (24u << 20));     // 4 MiB @24
  ushort* otb  = (ushort*)(ws);                   // 4 MiB @0  (reuse ht)
  ushort* wq   = (ushort*)(ws + (28u << 20));     // 384 KiB @28M
  ushort* wo   = (ushort*)(ws + (28u << 20) + (512u << 10));  // 128 KiB

  gnw_kernel<<<384, 512, 0, stream>>>(x, gamma, beta, dw,
                                      (const float4*)qkv_w, (const float4*)out_w,
                                      (uint2*)wq, (uint2*)wo, ht);
  qkv_fused_kernel<<<dim3(16, 8, B_), 256, 0, stream>>>(ht, wq, qkv_b, qtb, ktb, vbb);
  attn_mfma_kernel<<<512, 512, 0, stream>>>(qtb, ktb, vbb, otb);
  outconv_kernel<<<dim3(8, 4, B_), 256, 0, stream>>>(otb, wo, out_b, x, out);
}

// Round 21
// 53.581 us; speedup vs baseline: 1.0817x; 1.0606x over previous
//
#include <hip/hip_runtime.h>
#include <hip/hip_bf16.h>

#define B_ 8
#define C_ 256
#define L_ 1024
#define NH_ 8
#define EPS_ 1e-5f

typedef __attribute__((ext_vector_type(8))) _Float16 half8;
typedef __attribute__((ext_vector_type(2))) __fp16 fp16x2;
typedef __attribute__((ext_vector_type(4))) float f32x4;

static __device__ inline ushort f2h(float f) {
  union { _Float16 h; ushort u; } c;
  c.h = (_Float16)f;
  return c.u;
}

// pack two fp32 -> fp16 pair via v_cvt_pkrtz_f16_f32 (compiler builtin --
// safe on TRANS-result inputs, unlike inline asm; rounds 9-11 lesson)
static __device__ inline uint pkh(float a, float b) {
  union { fp16x2 v; uint u; } c;
  c.v = __builtin_amdgcn_cvt_pkrtz(a, b);
  return c.u;
}

// ---------------------------------------------------------------------------
// Kernel A (512 threads): blocks 0-127: weight fp32->fp16 convert;
// blocks 128-383: GroupNorm + depthwise conv k=3. ht [B][32 cg][1024 l][8 c].
// ---------------------------------------------------------------------------
__global__ __launch_bounds__(512) void gnw_kernel(
    const float* __restrict__ x, const float* __restrict__ gamma,
    const float* __restrict__ beta, const float* __restrict__ dw,
    const float4* __restrict__ qw, const float4* __restrict__ ow,
    uint2* __restrict__ wq, uint2* __restrict__ wo_,
    ushort* __restrict__ ht) {
  __shared__ float hn[8 * L_];
  __shared__ float ws0[8], ws1[8];
  int t = threadIdx.x;
  if (blockIdx.x < 128) {
    int id = blockIdx.x * 512 + t;
    float4 v;
    uint2* dst;
    if (id < 49152) { v = qw[id]; dst = wq + id; }
    else { v = ow[id - 49152]; dst = wo_ + (id - 49152); }
    *dst = make_uint2(pkh(v.x, v.y), pkh(v.z, v.w));
    return;
  }
  int blk = blockIdx.x - 128;     // b*32 + g
  int b = blk >> 5, g = blk & 31;
  const size_t base = ((size_t)(b * C_ + g * 8)) * L_;

  float s = 0.f, ss = 0.f;
  float vals[16];
#pragma unroll
  for (int i = 0; i < 16; ++i) {
    int e = t + 512 * i;
    float v = x[base + e];
    vals[i] = v;
    s += v; ss += v * v;
  }
#pragma unroll
  for (int off = 32; off >= 1; off >>= 1) {
    s  += __shfl_xor(s, off);
    ss += __shfl_xor(ss, off);
  }
  int wave = t >> 6;
  if ((t & 63) == 0) { ws0[wave] = s; ws1[wave] = ss; }
  __syncthreads();
  s = 0.f; ss = 0.f;
#pragma unroll
  for (int i = 0; i < 8; ++i) { s += ws0[i]; ss += ws1[i]; }
  float mean = s * (1.f / 8192.f);
  float var = ss * (1.f / 8192.f) - mean * mean;
  float rstd = rsqrtf(var + EPS_);

#pragma unroll
  for (int i = 0; i < 16; ++i) {
    int e = t + 512 * i;
    int c = g * 8 + (i >> 1);
    float sc = gamma[c] * rstd;
    hn[e] = (vals[i] - mean) * sc + beta[c];
  }
  __syncthreads();
  float r[16];
#pragma unroll
  for (int i = 0; i < 16; ++i) {
    int e = t + 512 * i;
    int l = e & 1023;
    int c = g * 8 + (i >> 1);
    float w0 = dw[c * 3 + 0], w1 = dw[c * 3 + 1], w2 = dw[c * 3 + 2];
    float a = (l > 0) ? hn[e - 1] : 0.f;
    float m = hn[e];
    float z = (l < 1023) ? hn[e + 1] : 0.f;
    r[i] = w0 * a + w1 * m + w2 * z;
  }
#pragma unroll
  for (int li = 0; li < 2; ++li) {
    int l = t + 512 * li;
    uint4 pk;
    pk.x = pkh(r[0 + li],  r[2 + li]);
    pk.y = pkh(r[4 + li],  r[6 + li]);
    pk.z = pkh(r[8 + li],  r[10 + li]);
    pk.w = pkh(r[12 + li], r[14 + li]);
    *(uint4*)(ht + (((size_t)(b * 32 + g)) * L_ + l) * 8) = pk;
  }
}

// ---------------------------------------------------------------------------
// Kernel B: qkv pointwise conv via MFMA (fp16), fused repack epilogue.
// Block = 128l x 96oc (4 waves of 64l x 48oc, acc[4][3]), grid (8, 8, 8).
// Input ht [B][32][1024][8]. Q PRE-SCALED by 1/sqrt(C)*log2(e).
// ---------------------------------------------------------------------------
__global__ __launch_bounds__(256) void qkv_fused_kernel(
    const ushort* __restrict__ Xt, const ushort* __restrict__ Wb,
    const float* __restrict__ bias, ushort* __restrict__ qt,
    ushort* __restrict__ kt, ushort* __restrict__ vb) {
  int bx = blockIdx.x, head = blockIdx.y, b = blockIdx.z;
  int bh = b * 8 + head;
  int t = threadIdx.x;
  int w = t >> 6, l = t & 63;
  int g = l >> 4, ln = l & 15;
  int wl = w >> 1, wo = w & 1;
  int lbase = bx * 128 + wl * 64;

  const ushort* xb = Xt + (size_t)b * (32 * L_ * 8);
  const ushort* wp = Wb + (size_t)(head * 96 + wo * 48) * 256;

  f32x4 acc[4][3];
#pragma unroll
  for (int ml = 0; ml < 4; ++ml)
#pragma unroll
    for (int nn = 0; nn < 3; ++nn) acc[ml][nn] = (f32x4){0.f, 0.f, 0.f, 0.f};

  for (int c0 = 0; c0 < 256; c0 += 32) {
    half8 af[4], bf[3];
#pragma unroll
    for (int ml = 0; ml < 4; ++ml)
      af[ml] = *(const half8*)(xb +
          (((size_t)((c0 >> 3) + g)) * L_ + lbase + 16 * ml + ln) * 8);
#pragma unroll
    for (int nn = 0; nn < 3; ++nn)
      bf[nn] = *(const half8*)(wp + (size_t)(16 * nn + ln) * 256 + c0 + 8 * g);
#pragma unroll
    for (int ml = 0; ml < 4; ++ml)
#pragma unroll
      for (int nn = 0; nn < 3; ++nn)
        acc[ml][nn] = __builtin_amdgcn_mfma_f32_16x16x32_f16(af[ml], bf[nn], acc[ml][nn], 0, 0, 0);
  }

  // bias
#pragma unroll
  for (int nn = 0; nn < 3; ++nn) {
    float bs = bias[head * 96 + wo * 48 + 16 * nn + ln];
#pragma unroll
    for (int ml = 0; ml < 4; ++ml)
#pragma unroll
      for (int r = 0; r < 4; ++r) acc[ml][nn][r] += bs;
  }

  __shared__ ushort tr[5120];
  const float QSC = 0.0625f * 1.44269504f;   // 1/sqrt(256) * log2(e)

  // rounds 0 (q, scaled), 1 (k): transpose to [l][d] (pad 40), write [bh][l][32]
  for (int rk = 0; rk < 2; ++rk) {
    float sc = rk ? 1.f : QSC;
    __syncthreads();
#pragma unroll
    for (int nn = 0; nn < 3; ++nn) {
      int ocl0 = wo * 48 + 16 * nn;
      if (ocl0 >= rk * 32 && ocl0 < rk * 32 + 32) {
        int d = ocl0 - rk * 32 + ln;
#pragma unroll
        for (int ml = 0; ml < 4; ++ml) {
          int lrow = wl * 64 + 16 * ml + 4 * g;
#pragma unroll
          for (int r = 0; r < 4; ++r)
            tr[(lrow + r) * 40 + d] = f2h(acc[ml][nn][r] * sc);
        }
      }
    }
    __syncthreads();
    {
      int row = t >> 1, half = t & 1;
      uint4 v0 = *(const uint4*)&tr[row * 40 + half * 16];
      uint4 v1 = *(const uint4*)&tr[row * 40 + half * 16 + 8];
      ushort* dst = (rk ? kt : qt) +
                    ((size_t)bh * L_ + bx * 128 + row) * 32 + half * 16;
      *(uint4*)dst = v0;
      *(uint4*)(dst + 8) = v1;
    }
  }

  // round 2 (v): [d][l] (pad 136), PI-permute on global write
  __syncthreads();
  if (wo == 1) {
#pragma unroll
    for (int nn = 1; nn < 3; ++nn) {
      int d = 16 * (nn - 1) + ln;
#pragma unroll
      for (int ml = 0; ml < 4; ++ml) {
        int lc = wl * 64 + 16 * ml + 4 * g;
        *(uint2*)&tr[d * 136 + lc] =
            make_uint2(pkh(acc[ml][nn][0], acc[ml][nn][1]),
                       pkh(acc[ml][nn][2], acc[ml][nn][3]));
      }
    }
  }
  __syncthreads();
  {
    int d = t >> 3, s0 = t & 7;
    ushort* vdst = vb + ((size_t)bh * 32 + d) * L_ + bx * 128;
#pragma unroll
    for (int c = 0; c < 2; ++c) {
      int ch = s0 + 8 * c;
      int jj = ch >> 2, gg = ch & 3;
      uint2 lo = *(const uint2*)&tr[d * 136 + 32 * jj + 4 * gg];
      uint2 hi = *(const uint2*)&tr[d * 136 + 32 * jj + 16 + 4 * gg];
      *(uint4*)(vdst + 32 * jj + 8 * gg) = make_uint4(lo.x, lo.y, hi.x, hi.y);
    }
  }
}

// ---------------------------------------------------------------------------
// Kernel D: out pointwise conv via MFMA (fp16) + residual. Input ot
// [bh][1024][32]. Block = 128 l x 64 oc. grid (8, 4, B) = 256.
// ---------------------------------------------------------------------------
__global__ __launch_bounds__(256) void outconv_kernel(
    const ushort* __restrict__ Xt, const ushort* __restrict__ Wb,
    const float* __restrict__ bias, const float* __restrict__ resid,
    float* __restrict__ out) {
  int b = blockIdx.z;
  int t = threadIdx.x;
  int w = t >> 6, l = t & 63;
  int g = l >> 4, ln = l & 15;
  int lbase = blockIdx.x * 128;
  int ocblk = blockIdx.y * 64;
  int ocbase = ocblk + w * 16;

  const ushort* xb = Xt + (size_t)b * (8 * L_ * 32);
  const ushort* wp = Wb + (size_t)ocbase * 256;

  f32x4 acc[8];
#pragma unroll
  for (int ml = 0; ml < 8; ++ml) acc[ml] = (f32x4){0.f, 0.f, 0.f, 0.f};

  for (int c0 = 0; c0 < 256; c0 += 32) {
    half8 af[8];
#pragma unroll
    for (int ml = 0; ml < 8; ++ml)
      af[ml] = *(const half8*)(xb +
          ((size_t)(c0 >> 5) * L_ + lbase + 16 * ml + ln) * 32 + 8 * g);
    half8 bf = *(const half8*)(wp + (size_t)ln * 256 + c0 + 8 * g);
#pragma unroll
    for (int ml = 0; ml < 8; ++ml)
      acc[ml] = __builtin_amdgcn_mfma_f32_16x16x32_f16(af[ml], bf, acc[ml], 0, 0, 0);
  }

  __shared__ float tile[64][132];   // 33 KB
  float bs = bias[ocbase + ln];
#pragma unroll
  for (int ml = 0; ml < 8; ++ml) {
    int ll = 16 * ml + 4 * g;
    float4 v = make_float4(acc[ml][0] + bs, acc[ml][1] + bs,
                           acc[ml][2] + bs, acc[ml][3] + bs);
    *(float4*)&tile[w * 16 + ln][ll] = v;
  }
  __syncthreads();
  {
    int ocl = t >> 2, lq = t & 3;           // 64 oc x 4 l-chunks of 32
    const float* src = &tile[ocl][lq * 32];
    size_t ob = ((size_t)b * 256 + ocblk + ocl) * L_ + lbase + lq * 32;
#pragma unroll
    for (int i = 0; i < 8; ++i) {
      float4 v = *(const float4*)(src + 4 * i);
      float4 rd = *(const float4*)(resid + ob + 4 * i);
      v.x += rd.x; v.y += rd.y; v.z += rd.z; v.w += rd.w;
      *(float4*)(out + ob + 4 * i) = v;
    }
  }
}

// ---------------------------------------------------------------------------
// Kernel C: MFMA flash attention, 8 waves x 16q = 128q per block (512 thr).
// fp16 pipeline, no max-subtraction, exp via v_exp_f32, pack via cvt_pkrtz.
// dbuf K+V LDS staging, padded layouts, otile overlays K0. grid 512.
// ---------------------------------------------------------------------------
__global__ __launch_bounds__(512) void attn_mfma_kernel(
    const ushort* __restrict__ qt, const ushort* __restrict__ kt,
    const ushort* __restrict__ vb, ushort* __restrict__ ot) {
  const int id = blockIdx.x;
  const int bh = ((id & 7) << 3) | (id >> 6);
  const int qtile = (id >> 3) & 7;
  const int t = threadIdx.x;
  const int w = t >> 6, l = t & 63;
  const int g = l >> 4, ln = l & 15;
  const int q0b = qtile * 128;
  const int q0 = q0b + w * 16;

  // smem (ushorts): K0 @0 (5120), K1 @5120, V0 @10240 (4352), V1 @14592.
  // otile [128][40] = 5120 overlays K0 (dead in tt=7 / epilogue).
  __shared__ __align__(16) ushort smem[18944];   // 37,888 B

  const ushort* qbase = qt + (size_t)bh * (L_ * 32);
  const ushort* kbase = kt + (size_t)bh * (L_ * 32);
  const ushort* vbase = vb + (size_t)bh * (32 * L_);

  // staging geometry (512 threads, 1 x 16B each for K and V per tile)
  const int krow = t >> 2, kchunk = t & 3;           // K: 128 rows x 4 chunks
  const ushort* kg = kbase + krow * 32 + kchunk * 8;
  const int kwo = krow * 40 + kchunk * 8;
  const int vrow = t >> 4, vchunk = t & 15;          // V: 32 rows x 16 chunks
  const ushort* vg = vbase + (size_t)vrow * L_ + vchunk * 8;
  const int vwo = vrow * 136 + vchunk * 8;

  const f32x4 z4 = {0.f, 0.f, 0.f, 0.f};
  const half8 bq = *(const half8*)(qbase + (size_t)(q0 + ln) * 32 + g * 8);

  union { ushort s[8]; half8 v; } onesu;
#pragma unroll
  for (int i = 0; i < 8; ++i) onesu.s[i] = 0x3C00;  // fp16 1.0
  const half8 ones = onesu.v;

  f32x4 oacc[2] = {z4, z4};   // [md]
  f32x4 oaccS = z4;

  // prologue: stage tile 0
  uint4 ka0, va0;
  ka0 = *(const uint4*)kg;
  va0 = *(const uint4*)vg;
  __builtin_amdgcn_sched_barrier(0);
  *(uint4*)&smem[kwo] = ka0;
  *(uint4*)&smem[10240 + vwo] = va0;
  asm volatile("s_waitcnt lgkmcnt(0)" ::: "memory");
  __builtin_amdgcn_s_barrier();
  __builtin_amdgcn_sched_barrier(0);

  for (int tt = 0; tt < 8; ++tt) {
    const int cur = tt & 1;
    if (tt < 7) {
      ka0 = *(const uint4*)(kg + (tt + 1) * 4096);
      va0 = *(const uint4*)(vg + (tt + 1) * 128);
    }
    __builtin_amdgcn_sched_barrier(0);

    const ushort* Kc = &smem[cur * 5120];
    const ushort* Vc = &smem[10240 + cur * 4352];

    // QK^T  (S already in log2-units thanks to Q pre-scale)
    f32x4 sacc[8];
#pragma unroll
    for (int mk = 0; mk < 8; ++mk) {
      half8 ak = *(const half8*)(Kc + (16 * mk + ln) * 40 + g * 8);
      sacc[mk] = __builtin_amdgcn_mfma_f32_16x16x32_f16(ak, bq, z4, 0, 0, 0);
    }

    // exp via v_exp_f32; pack pairs via cvt_pkrtz (compiler builtin -- safe
    // TRANS consumer)
    uint upk[8][2];
#pragma unroll
    for (int mk = 0; mk < 8; ++mk) {
      float e0 = __builtin_amdgcn_exp2f(sacc[mk][0]);
      float e1 = __builtin_amdgcn_exp2f(sacc[mk][1]);
      float e2 = __builtin_amdgcn_exp2f(sacc[mk][2]);
      float e3 = __builtin_amdgcn_exp2f(sacc[mk][3]);
      upk[mk][0] = pkh(e0, e1);
      upk[mk][1] = pkh(e2, e3);
    }

    // PV + denominator
#pragma unroll
    for (int ks = 0; ks < 4; ++ks) {
      union { uint u[4]; half8 v; } pb;
      pb.u[0] = upk[2 * ks][0];     pb.u[1] = upk[2 * ks][1];
      pb.u[2] = upk[2 * ks + 1][0]; pb.u[3] = upk[2 * ks + 1][1];
      oaccS = __builtin_amdgcn_mfma_f32_16x16x32_f16(ones, pb.v, oaccS, 0, 0, 0);
#pragma unroll
      for (int md = 0; md < 2; ++md) {
        half8 av = *(const half8*)(Vc + (16 * md + ln) * 136 + 32 * ks + 8 * g);
        oacc[md] = __builtin_amdgcn_mfma_f32_16x16x32_f16(av, pb.v, oacc[md], 0, 0, 0);
      }
    }

    __builtin_amdgcn_sched_barrier(0);
    if (tt < 7) {
      const int nxt = cur ^ 1;
      *(uint4*)&smem[nxt * 5120 + kwo] = ka0;
      *(uint4*)&smem[10240 + nxt * 4352 + vwo] = va0;
      asm volatile("s_waitcnt lgkmcnt(0)" ::: "memory");
      __builtin_amdgcn_s_barrier();
      __builtin_amdgcn_sched_barrier(0);
    }
  }

  // epilogue: normalize, LDS transpose (otile overlays K0), write ot[bh][l][32]
  ushort* otile = &smem[0];   // [128][40]
  float rl = 1.f / oaccS[0];
  int q_loc = w * 16 + ln;
#pragma unroll
  for (int md = 0; md < 2; ++md) {
    uint2 pk = make_uint2(pkh(oacc[md][0] * rl, oacc[md][1] * rl),
                          pkh(oacc[md][2] * rl, oacc[md][3] * rl));
    *(uint2*)&otile[q_loc * 40 + 16 * md + 4 * g] = pk;
  }
  __syncthreads();
  {
    int row = t >> 2, qu = t & 3;
    uint4 v = *(const uint4*)&otile[row * 40 + qu * 8];
    *(uint4*)(ot + ((size_t)bh * L_ + q0b + row) * 32 + qu * 8) = v;
  }
}

// ---------------------------------------------------------------------------
extern "C" void kernel_launch(void* const* d_in, const int* in_sizes, int n_in,
                              void* d_out, int out_size, void* d_ws, size_t ws_size,
                              hipStream_t stream) {
  const float* x      = (const float*)d_in[0];
  const float* gamma  = (const float*)d_in[1];
  const float* beta   = (const float*)d_in[2];
  const float* dw     = (const float*)d_in[3];
  const float* qkv_w  = (const float*)d_in[4];
  const float* qkv_b  = (const float*)d_in[5];
  const float* out_w  = (const float*)d_in[6];
  const float* out_b  = (const float*)d_in[7];
  float* out = (float*)d_out;

  char* ws = (char*)d_ws;
  ushort* ht   = (ushort*)(ws);                   // 4 MiB @0  (dead after qkv)
  ushort* qtb  = (ushort*)(ws + (16u << 20));     // 4 MiB @16
  ushort* ktb  = (ushort*)(ws + (20u << 20));     // 4 MiB @20
  ushort* vbb  = (ushort*)(ws + (24u << 20));     // 4 MiB @24
  ushort* otb  = (ushort*)(ws);                   // 4 MiB @0  (reuse ht)
  ushort* wq   = (ushort*)(ws + (28u << 20));     // 384 KiB @28M
  ushort* wo   = (ushort*)(ws + (28u << 20) + (512u << 10));  // 128 KiB

  gnw_kernel<<<384, 512, 0, stream>>>(x, gamma, beta, dw,
                                      (const float4*)qkv_w, (const float4*)out_w,
                                      (uint2*)wq, (uint2*)wo, ht);
  qkv_fused_kernel<<<dim3(8, 8, B_), 256, 0, stream>>>(ht, wq, qkv_b, qtb, ktb, vbb);
  attn_mfma_kernel<<<512, 512, 0, stream>>>(qtb, ktb, vbb, otb);
  outconv_kernel<<<dim3(8, 4, B_), 256, 0, stream>>>(otb, wo, out_b, x, out);
}

// Round 22
// 53.343 us; speedup vs baseline: 1.0866x; 1.0045x over previous
//
#include <hip/hip_runtime.h>
#include <hip/hip_bf16.h>

#define B_ 8
#define C_ 256
#define L_ 1024
#define NH_ 8
#define EPS_ 1e-5f

typedef __attribute__((ext_vector_type(8))) _Float16 half8;
typedef __attribute__((ext_vector_type(2))) __fp16 fp16x2;
typedef __attribute__((ext_vector_type(4))) float f32x4;

static __device__ inline ushort f2h(float f) {
  union { _Float16 h; ushort u; } c;
  c.h = (_Float16)f;
  return c.u;
}

// pack two fp32 -> fp16 pair via v_cvt_pkrtz_f16_f32 (compiler builtin --
// safe on TRANS-result inputs, unlike inline asm; rounds 9-11 lesson)
static __device__ inline uint pkh(float a, float b) {
  union { fp16x2 v; uint u; } c;
  c.v = __builtin_amdgcn_cvt_pkrtz(a, b);
  return c.u;
}

// ---------------------------------------------------------------------------
// Kernel A (512 threads): blocks 0-127: weight fp32->fp16 convert;
// blocks 128-383: GroupNorm + depthwise conv k=3. ht [B][32 cg][1024 l][8 c].
// x loaded as float4 (16B/lane, G13) -- only delta vs round-21.
// ---------------------------------------------------------------------------
__global__ __launch_bounds__(512) void gnw_kernel(
    const float* __restrict__ x, const float* __restrict__ gamma,
    const float* __restrict__ beta, const float* __restrict__ dw,
    const float4* __restrict__ qw, const float4* __restrict__ ow,
    uint2* __restrict__ wq, uint2* __restrict__ wo_,
    ushort* __restrict__ ht) {
  __shared__ float hn[8 * L_];
  __shared__ float ws0[8], ws1[8];
  int t = threadIdx.x;
  if (blockIdx.x < 128) {
    int id = blockIdx.x * 512 + t;
    float4 v;
    uint2* dst;
    if (id < 49152) { v = qw[id]; dst = wq + id; }
    else { v = ow[id - 49152]; dst = wo_ + (id - 49152); }
    *dst = make_uint2(pkh(v.x, v.y), pkh(v.z, v.w));
    return;
  }
  int blk = blockIdx.x - 128;     // b*32 + g
  int b = blk >> 5, g = blk & 31;
  const size_t base = ((size_t)(b * C_ + g * 8)) * L_;

  // float4 loads: f = t + 512*i covers 2048 float4 = 8192 floats
  const float4* x4 = (const float4*)(x + base);
  float s = 0.f, ss = 0.f;
  float4 vals[4];
#pragma unroll
  for (int i = 0; i < 4; ++i) {
    float4 v = x4[t + 512 * i];
    vals[i] = v;
    s += v.x + v.y + v.z + v.w;
    ss += v.x * v.x + v.y * v.y + v.z * v.z + v.w * v.w;
  }
#pragma unroll
  for (int off = 32; off >= 1; off >>= 1) {
    s  += __shfl_xor(s, off);
    ss += __shfl_xor(ss, off);
  }
  int wave = t >> 6;
  if ((t & 63) == 0) { ws0[wave] = s; ws1[wave] = ss; }
  __syncthreads();
  s = 0.f; ss = 0.f;
#pragma unroll
  for (int i = 0; i < 8; ++i) { s += ws0[i]; ss += ws1[i]; }
  float mean = s * (1.f / 8192.f);
  float var = ss * (1.f / 8192.f) - mean * mean;
  float rstd = rsqrtf(var + EPS_);

  // element e = 4t + 2048*i (+j); channel c = g*8 + 2i + (t>>8), wave-uniform
  int chalf = t >> 8;
#pragma unroll
  for (int i = 0; i < 4; ++i) {
    int c = g * 8 + 2 * i + chalf;
    float sc = gamma[c] * rstd;
    float bt = beta[c];
    float4 v = vals[i];
    float4 h = make_float4((v.x - mean) * sc + bt, (v.y - mean) * sc + bt,
                           (v.z - mean) * sc + bt, (v.w - mean) * sc + bt);
    *(float4*)&hn[4 * t + 2048 * i] = h;
  }
  __syncthreads();
  float r[16];
#pragma unroll
  for (int i = 0; i < 16; ++i) {
    int e = t + 512 * i;
    int l = e & 1023;
    int c = g * 8 + (i >> 1);
    float w0 = dw[c * 3 + 0], w1 = dw[c * 3 + 1], w2 = dw[c * 3 + 2];
    float a = (l > 0) ? hn[e - 1] : 0.f;
    float m = hn[e];
    float z = (l < 1023) ? hn[e + 1] : 0.f;
    r[i] = w0 * a + w1 * m + w2 * z;
  }
#pragma unroll
  for (int li = 0; li < 2; ++li) {
    int l = t + 512 * li;
    uint4 pk;
    pk.x = pkh(r[0 + li],  r[2 + li]);
    pk.y = pkh(r[4 + li],  r[6 + li]);
    pk.z = pkh(r[8 + li],  r[10 + li]);
    pk.w = pkh(r[12 + li], r[14 + li]);
    *(uint4*)(ht + (((size_t)(b * 32 + g)) * L_ + l) * 8) = pk;
  }
}

// ---------------------------------------------------------------------------
// Kernel B: qkv pointwise conv via MFMA (fp16), fused repack epilogue.
// Block = 128l x 96oc (4 waves of 64l x 48oc, acc[4][3]), grid (8, 8, 8).
// Input ht [B][32][1024][8]. Q PRE-SCALED by 1/sqrt(C)*log2(e).
// ---------------------------------------------------------------------------
__global__ __launch_bounds__(256) void qkv_fused_kernel(
    const ushort* __restrict__ Xt, const ushort* __restrict__ Wb,
    const float* __restrict__ bias, ushort* __restrict__ qt,
    ushort* __restrict__ kt, ushort* __restrict__ vb) {
  int bx = blockIdx.x, head = blockIdx.y, b = blockIdx.z;
  int bh = b * 8 + head;
  int t = threadIdx.x;
  int w = t >> 6, l = t & 63;
  int g = l >> 4, ln = l & 15;
  int wl = w >> 1, wo = w & 1;
  int lbase = bx * 128 + wl * 64;

  const ushort* xb = Xt + (size_t)b * (32 * L_ * 8);
  const ushort* wp = Wb + (size_t)(head * 96 + wo * 48) * 256;

  f32x4 acc[4][3];
#pragma unroll
  for (int ml = 0; ml < 4; ++ml)
#pragma unroll
    for (int nn = 0; nn < 3; ++nn) acc[ml][nn] = (f32x4){0.f, 0.f, 0.f, 0.f};

  for (int c0 = 0; c0 < 256; c0 += 32) {
    half8 af[4], bf[3];
#pragma unroll
    for (int ml = 0; ml < 4; ++ml)
      af[ml] = *(const half8*)(xb +
          (((size_t)((c0 >> 3) + g)) * L_ + lbase + 16 * ml + ln) * 8);
#pragma unroll
    for (int nn = 0; nn < 3; ++nn)
      bf[nn] = *(const half8*)(wp + (size_t)(16 * nn + ln) * 256 + c0 + 8 * g);
#pragma unroll
    for (int ml = 0; ml < 4; ++ml)
#pragma unroll
      for (int nn = 0; nn < 3; ++nn)
        acc[ml][nn] = __builtin_amdgcn_mfma_f32_16x16x32_f16(af[ml], bf[nn], acc[ml][nn], 0, 0, 0);
  }

  // bias
#pragma unroll
  for (int nn = 0; nn < 3; ++nn) {
    float bs = bias[head * 96 + wo * 48 + 16 * nn + ln];
#pragma unroll
    for (int ml = 0; ml < 4; ++ml)
#pragma unroll
      for (int r = 0; r < 4; ++r) acc[ml][nn][r] += bs;
  }

  __shared__ ushort tr[5120];
  const float QSC = 0.0625f * 1.44269504f;   // 1/sqrt(256) * log2(e)

  // rounds 0 (q, scaled), 1 (k): transpose to [l][d] (pad 40), write [bh][l][32]
  for (int rk = 0; rk < 2; ++rk) {
    float sc = rk ? 1.f : QSC;
    __syncthreads();
#pragma unroll
    for (int nn = 0; nn < 3; ++nn) {
      int ocl0 = wo * 48 + 16 * nn;
      if (ocl0 >= rk * 32 && ocl0 < rk * 32 + 32) {
        int d = ocl0 - rk * 32 + ln;
#pragma unroll
        for (int ml = 0; ml < 4; ++ml) {
          int lrow = wl * 64 + 16 * ml + 4 * g;
#pragma unroll
          for (int r = 0; r < 4; ++r)
            tr[(lrow + r) * 40 + d] = f2h(acc[ml][nn][r] * sc);
        }
      }
    }
    __syncthreads();
    {
      int row = t >> 1, half = t & 1;
      uint4 v0 = *(const uint4*)&tr[row * 40 + half * 16];
      uint4 v1 = *(const uint4*)&tr[row * 40 + half * 16 + 8];
      ushort* dst = (rk ? kt : qt) +
                    ((size_t)bh * L_ + bx * 128 + row) * 32 + half * 16;
      *(uint4*)dst = v0;
      *(uint4*)(dst + 8) = v1;
    }
  }

  // round 2 (v): [d][l] (pad 136), PI-permute on global write
  __syncthreads();
  if (wo == 1) {
#pragma unroll
    for (int nn = 1; nn < 3; ++nn) {
      int d = 16 * (nn - 1) + ln;
#pragma unroll
      for (int ml = 0; ml < 4; ++ml) {
        int lc = wl * 64 + 16 * ml + 4 * g;
        *(uint2*)&tr[d * 136 + lc] =
            make_uint2(pkh(acc[ml][nn][0], acc[ml][nn][1]),
                       pkh(acc[ml][nn][2], acc[ml][nn][3]));
      }
    }
  }
  __syncthreads();
  {
    int d = t >> 3, s0 = t & 7;
    ushort* vdst = vb + ((size_t)bh * 32 + d) * L_ + bx * 128;
#pragma unroll
    for (int c = 0; c < 2; ++c) {
      int ch = s0 + 8 * c;
      int jj = ch >> 2, gg = ch & 3;
      uint2 lo = *(const uint2*)&tr[d * 136 + 32 * jj + 4 * gg];
      uint2 hi = *(const uint2*)&tr[d * 136 + 32 * jj + 16 + 4 * gg];
      *(uint4*)(vdst + 32 * jj + 8 * gg) = make_uint4(lo.x, lo.y, hi.x, hi.y);
    }
  }
}

// ---------------------------------------------------------------------------
// Kernel D: out pointwise conv via MFMA (fp16) + residual. Input ot
// [bh][1024][32]. Block = 128 l x 64 oc. grid (8, 4, B) = 256.
// ---------------------------------------------------------------------------
__global__ __launch_bounds__(256) void outconv_kernel(
    const ushort* __restrict__ Xt, const ushort* __restrict__ Wb,
    const float* __restrict__ bias, const float* __restrict__ resid,
    float* __restrict__ out) {
  int b = blockIdx.z;
  int t = threadIdx.x;
  int w = t >> 6, l = t & 63;
  int g = l >> 4, ln = l & 15;
  int lbase = blockIdx.x * 128;
  int ocblk = blockIdx.y * 64;
  int ocbase = ocblk + w * 16;

  const ushort* xb = Xt + (size_t)b * (8 * L_ * 32);
  const ushort* wp = Wb + (size_t)ocbase * 256;

  f32x4 acc[8];
#pragma unroll
  for (int ml = 0; ml < 8; ++ml) acc[ml] = (f32x4){0.f, 0.f, 0.f, 0.f};

  for (int c0 = 0; c0 < 256; c0 += 32) {
    half8 af[8];
#pragma unroll
    for (int ml = 0; ml < 8; ++ml)
      af[ml] = *(const half8*)(xb +
          ((size_t)(c0 >> 5) * L_ + lbase + 16 * ml + ln) * 32 + 8 * g);
    half8 bf = *(const half8*)(wp + (size_t)ln * 256 + c0 + 8 * g);
#pragma unroll
    for (int ml = 0; ml < 8; ++ml)
      acc[ml] = __builtin_amdgcn_mfma_f32_16x16x32_f16(af[ml], bf, acc[ml], 0, 0, 0);
  }

  __shared__ float tile[64][132];   // 33 KB
  float bs = bias[ocbase + ln];
#pragma unroll
  for (int ml = 0; ml < 8; ++ml) {
    int ll = 16 * ml + 4 * g;
    float4 v = make_float4(acc[ml][0] + bs, acc[ml][1] + bs,
                           acc[ml][2] + bs, acc[ml][3] + bs);
    *(float4*)&tile[w * 16 + ln][ll] = v;
  }
  __syncthreads();
  {
    int ocl = t >> 2, lq = t & 3;           // 64 oc x 4 l-chunks of 32
    const float* src = &tile[ocl][lq * 32];
    size_t ob = ((size_t)b * 256 + ocblk + ocl) * L_ + lbase + lq * 32;
#pragma unroll
    for (int i = 0; i < 8; ++i) {
      float4 v = *(const float4*)(src + 4 * i);
      float4 rd = *(const float4*)(resid + ob + 4 * i);
      v.x += rd.x; v.y += rd.y; v.z += rd.z; v.w += rd.w;
      *(float4*)(out + ob + 4 * i) = v;
    }
  }
}

// ---------------------------------------------------------------------------
// Kernel C: MFMA flash attention, 8 waves x 16q = 128q per block (512 thr).
// fp16 pipeline, no max-subtraction, exp via v_exp_f32, pack via cvt_pkrtz.
// dbuf K+V LDS staging, padded layouts, otile overlays K0. grid 512.
// ---------------------------------------------------------------------------
__global__ __launch_bounds__(512) void attn_mfma_kernel(
    const ushort* __restrict__ qt, const ushort* __restrict__ kt,
    const ushort* __restrict__ vb, ushort* __restrict__ ot) {
  const int id = blockIdx.x;
  const int bh = ((id & 7) << 3) | (id >> 6);
  const int qtile = (id >> 3) & 7;
  const int t = threadIdx.x;
  const int w = t >> 6, l = t & 63;
  const int g = l >> 4, ln = l & 15;
  const int q0b = qtile * 128;
  const int q0 = q0b + w * 16;

  // smem (ushorts): K0 @0 (5120), K1 @5120, V0 @10240 (4352), V1 @14592.
  // otile [128][40] = 5120 overlays K0 (dead in tt=7 / epilogue).
  __shared__ __align__(16) ushort smem[18944];   // 37,888 B

  const ushort* qbase = qt + (size_t)bh * (L_ * 32);
  const ushort* kbase = kt + (size_t)bh * (L_ * 32);
  const ushort* vbase = vb + (size_t)bh * (32 * L_);

  // staging geometry (512 threads, 1 x 16B each for K and V per tile)
  const int krow = t >> 2, kchunk = t & 3;           // K: 128 rows x 4 chunks
  const ushort* kg = kbase + krow * 32 + kchunk * 8;
  const int kwo = krow * 40 + kchunk * 8;
  const int vrow = t >> 4, vchunk = t & 15;          // V: 32 rows x 16 chunks
  const ushort* vg = vbase + (size_t)vrow * L_ + vchunk * 8;
  const int vwo = vrow * 136 + vchunk * 8;

  const f32x4 z4 = {0.f, 0.f, 0.f, 0.f};
  const half8 bq = *(const half8*)(qbase + (size_t)(q0 + ln) * 32 + g * 8);

  union { ushort s[8]; half8 v; } onesu;
#pragma unroll
  for (int i = 0; i < 8; ++i) onesu.s[i] = 0x3C00;  // fp16 1.0
  const half8 ones = onesu.v;

  f32x4 oacc[2] = {z4, z4};   // [md]
  f32x4 oaccS = z4;

  // prologue: stage tile 0
  uint4 ka0, va0;
  ka0 = *(const uint4*)kg;
  va0 = *(const uint4*)vg;
  __builtin_amdgcn_sched_barrier(0);
  *(uint4*)&smem[kwo] = ka0;
  *(uint4*)&smem[10240 + vwo] = va0;
  asm volatile("s_waitcnt lgkmcnt(0)" ::: "memory");
  __builtin_amdgcn_s_barrier();
  __builtin_amdgcn_sched_barrier(0);

  for (int tt = 0; tt < 8; ++tt) {
    const int cur = tt & 1;
    if (tt < 7) {
      ka0 = *(const uint4*)(kg + (tt + 1) * 4096);
      va0 = *(const uint4*)(vg + (tt + 1) * 128);
    }
    __builtin_amdgcn_sched_barrier(0);

    const ushort* Kc = &smem[cur * 5120];
    const ushort* Vc = &smem[10240 + cur * 4352];

    // QK^T  (S already in log2-units thanks to Q pre-scale)
    f32x4 sacc[8];
#pragma unroll
    for (int mk = 0; mk < 8; ++mk) {
      half8 ak = *(const half8*)(Kc + (16 * mk + ln) * 40 + g * 8);
      sacc[mk] = __builtin_amdgcn_mfma_f32_16x16x32_f16(ak, bq, z4, 0, 0, 0);
    }

    // exp via v_exp_f32; pack pairs via cvt_pkrtz (compiler builtin -- safe
    // TRANS consumer)
    uint upk[8][2];
#pragma unroll
    for (int mk = 0; mk < 8; ++mk) {
      float e0 = __builtin_amdgcn_exp2f(sacc[mk][0]);
      float e1 = __builtin_amdgcn_exp2f(sacc[mk][1]);
      float e2 = __builtin_amdgcn_exp2f(sacc[mk][2]);
      float e3 = __builtin_amdgcn_exp2f(sacc[mk][3]);
      upk[mk][0] = pkh(e0, e1);
      upk[mk][1] = pkh(e2, e3);
    }

    // PV + denominator
#pragma unroll
    for (int ks = 0; ks < 4; ++ks) {
      union { uint u[4]; half8 v; } pb;
      pb.u[0] = upk[2 * ks][0];     pb.u[1] = upk[2 * ks][1];
      pb.u[2] = upk[2 * ks + 1][0]; pb.u[3] = upk[2 * ks + 1][1];
      oaccS = __builtin_amdgcn_mfma_f32_16x16x32_f16(ones, pb.v, oaccS, 0, 0, 0);
#pragma unroll
      for (int md = 0; md < 2; ++md) {
        half8 av = *(const half8*)(Vc + (16 * md + ln) * 136 + 32 * ks + 8 * g);
        oacc[md] = __builtin_amdgcn_mfma_f32_16x16x32_f16(av, pb.v, oacc[md], 0, 0, 0);
      }
    }

    __builtin_amdgcn_sched_barrier(0);
    if (tt < 7) {
      const int nxt = cur ^ 1;
      *(uint4*)&smem[nxt * 5120 + kwo] = ka0;
      *(uint4*)&smem[10240 + nxt * 4352 + vwo] = va0;
      asm volatile("s_waitcnt lgkmcnt(0)" ::: "memory");
      __builtin_amdgcn_s_barrier();
      __builtin_amdgcn_sched_barrier(0);
    }
  }

  // epilogue: normalize, LDS transpose (otile overlays K0), write ot[bh][l][32]
  ushort* otile = &smem[0];   // [128][40]
  float rl = 1.f / oaccS[0];
  int q_loc = w * 16 + ln;
#pragma unroll
  for (int md = 0; md < 2; ++md) {
    uint2 pk = make_uint2(pkh(oacc[md][0] * rl, oacc[md][1] * rl),
                          pkh(oacc[md][2] * rl, oacc[md][3] * rl));
    *(uint2*)&otile[q_loc * 40 + 16 * md + 4 * g] = pk;
  }
  __syncthreads();
  {
    int row = t >> 2, qu = t & 3;
    uint4 v = *(const uint4*)&otile[row * 40 + qu * 8];
    *(uint4*)(ot + ((size_t)bh * L_ + q0b + row) * 32 + qu * 8) = v;
  }
}

// ---------------------------------------------------------------------------
extern "C" void kernel_launch(void* const* d_in, const int* in_sizes, int n_in,
                              void* d_out, int out_size, void* d_ws, size_t ws_size,
                              hipStream_t stream) {
  const float* x      = (const float*)d_in[0];
  const float* gamma  = (const float*)d_in[1];
  const float* beta   = (const float*)d_in[2];
  const float* dw     = (const float*)d_in[3];
  const float* qkv_w  = (const float*)d_in[4];
  const float* qkv_b  = (const float*)d_in[5];
  const float* out_w  = (const float*)d_in[6];
  const float* out_b  = (const float*)d_in[7];
  float* out = (float*)d_out;

  char* ws = (char*)d_ws;
  ushort* ht   = (ushort*)(ws);                   // 4 MiB @0  (dead after qkv)
  ushort* qtb  = (ushort*)(ws + (16u << 20));     // 4 MiB @16
  ushort* ktb  = (ushort*)(ws + (20u << 20));     // 4 MiB @20
  ushort* vbb  = (ushort*)(ws + (24u << 20));     // 4 MiB @24
  ushort* otb  = (ushort*)(ws);                   // 4 MiB @0  (reuse ht)
  ushort* wq   = (ushort*)(ws + (28u << 20));     // 384 KiB @28M
  ushort* wo   = (ushort*)(ws + (28u << 20) + (512u << 10));  // 128 KiB

  gnw_kernel<<<384, 512, 0, stream>>>(x, gamma, beta, dw,
                                      (const float4*)qkv_w, (const float4*)out_w,
                                      (uint2*)wq, (uint2*)wo, ht);
  qkv_fused_kernel<<<dim3(8, 8, B_), 256, 0, stream>>>(ht, wq, qkv_b, qtb, ktb, vbb);
  attn_mfma_kernel<<<512, 512, 0, stream>>>(qtb, ktb, vbb, otb);
  outconv_kernel<<<dim3(8, 4, B_), 256, 0, stream>>>(otb, wo, out_b, x, out);
}